// Round 4
// baseline (563.892 us; speedup 1.0000x reference)
//
#include <hip/hip_runtime.h>
#include <stdint.h>

// Fused linear -> logsumexp -> NLL(sum), TOKENS x DMODEL @ (VOCAB x DMODEL)^T.
// Round 4: 8-phase counted-vmcnt schedule (T3+T4) on the 256x256xBK64 tile.
// Per K-tile: 4 phases {ds_read subtile | stage 1 half-tile -> raw s_barrier ->
// setprio+16 MFMA+setprio -> raw s_barrier}; ONE s_waitcnt vmcnt(4) per K-tile
// at the tile boundary (never vmcnt(0) in the main loop). Staging is race-free
// by last-reader analysis:
//   P0: stage A-half0(t+1) -> next buffer (region freed at (t-1).P2 barrier)
//   P1: stage A-half1(t+1) -> next buffer
//   P2: stage B-half0(t+2) -> CURRENT buffer (B last read in P1; barrier passed)
//   P3: stage B-half1(t+2) -> CURRENT buffer
// Boundary vmcnt(4) leaves exactly the 2 newest halves (B(t+2)) in flight and
// guarantees tile t+1 fully landed; + s_barrier makes it cooperative.

#define TOKENS 8192
#define DMODEL 1024
#define VOCAB  32000

// 128^2 fallback geometry (only if ws too small; never taken so far)
#define NBM    (TOKENS / 128)
#define NBN    (VOCAB / 128)
#define NWG    (NBM * NBN)
#define CHUNK  (NWG / 8)

// 256^2 main geometry
#define NBM2   (TOKENS / 256)   // 32
#define NBN2   (VOCAB / 256)    // 125
#define NWG2   (NBM2 * NBN2)    // 4000 = 8 bands x 500
#define HALF   8192             // u16 elems per 128x64 half-tile

typedef float  f32x4  __attribute__((ext_vector_type(4)));
typedef __bf16 bf16x8 __attribute__((ext_vector_type(8)));
typedef unsigned short u16;
typedef u16 u16x4 __attribute__((ext_vector_type(4)));
typedef u16 u16x8 __attribute__((ext_vector_type(8)));

__device__ __forceinline__ u16 f2bf(float f) {  // RNE fp32 -> bf16 bits
  union { float f; uint32_t u; } v; v.f = f;
  return (u16)((v.u + 0x7FFFu + ((v.u >> 16) & 1u)) >> 16);
}

__device__ __forceinline__ void g2lds16(const void* gsrc, void* ldst) {
  __builtin_amdgcn_global_load_lds(
      (const __attribute__((address_space(1))) uint32_t*)(uintptr_t)gsrc,
      (__attribute__((address_space(3))) uint32_t*)(uintptr_t)ldst,
      16, 0, 0);
}

__device__ __forceinline__ void bar() {
  asm volatile("" ::: "memory");
  __builtin_amdgcn_s_barrier();
  asm volatile("" ::: "memory");
}

template <int N> __device__ __forceinline__ void vmw() {
  if constexpr (N == 4)      asm volatile("s_waitcnt vmcnt(4)" ::: "memory");
  else if constexpr (N == 0) asm volatile("s_waitcnt vmcnt(0)" ::: "memory");
}

__global__ void convert_to_bf16(const float* __restrict__ in, u16* __restrict__ out,
                                long long n) {
  long long i0 = ((long long)blockIdx.x * blockDim.x + threadIdx.x) * 8;
  long long stride = (long long)gridDim.x * blockDim.x * 8;
  for (long long base = i0; base < n; base += stride) {
    float4 a = *(const float4*)(in + base);
    float4 b = *(const float4*)(in + base + 4);
    u16x8 r = { f2bf(a.x), f2bf(a.y), f2bf(a.z), f2bf(a.w),
                f2bf(b.x), f2bf(b.y), f2bf(b.z), f2bf(b.w) };
    *(u16x8*)(out + base) = r;
  }
}

// Stage one 128x64 half-tile: 2 g2lds16 per thread, pre-swizzled source,
// linear LDS dest (rule #21: swizzle source + read, dest linear).
__device__ __forceinline__ void stage_half(const u16* __restrict__ G, u16* L,
                                           int grow0, int k0, int wave, int lane) {
#pragma unroll
  for (int r = 0; r < 2; ++r) {
    const int c   = r * 8 + wave;           // chunk 0..15 = 8 rows each
    const int row = c * 8 + (lane >> 3);    // 0..127
    const int col = ((lane & 7) * 8) ^ ((row & 7) << 3);
    g2lds16(G + (size_t)(grow0 + row) * DMODEL + k0 + col, (void*)(L + c * 512));
  }
}

__device__ __forceinline__ void ldA4(const u16* base, bf16x8 (&a)[4][2], int roff,
                                     int wr, int l15, int kc0, int kc1) {
#pragma unroll
  for (int m = 0; m < 4; ++m) {
    const u16* p = base + (wr * 128 + roff + m * 16 + l15) * 64;
    a[m][0] = *(const bf16x8*)(p + kc0);
    a[m][1] = *(const bf16x8*)(p + kc1);
  }
}

#define MFMA_Q(AMOFF, N0)                                                      \
  __builtin_amdgcn_s_setprio(1);                                               \
  _Pragma("unroll")                                                            \
  for (int m = 0; m < 4; ++m) {                                                \
    _Pragma("unroll")                                                          \
    for (int n = 0; n < 2; ++n) {                                              \
      acc[AMOFF + m][N0 + n] = __builtin_amdgcn_mfma_f32_16x16x32_bf16(        \
          a[m][0], b[N0 + n][0], acc[AMOFF + m][N0 + n], 0, 0, 0);             \
      acc[AMOFF + m][N0 + n] = __builtin_amdgcn_mfma_f32_16x16x32_bf16(        \
          a[m][1], b[N0 + n][1], acc[AMOFF + m][N0 + n], 0, 0, 0);             \
    }                                                                          \
  }                                                                            \
  __builtin_amdgcn_s_setprio(0);

// One K-tile, 4 phases. curA/curB: buffer being read. nxtA: other buffer's A
// region (stage target for A(t+1)). B(t+2) staged into curB.
template <bool STAGE_A, bool STAGE_B, int BOUND>  // BOUND: 4, 0, or -1 (none)
__device__ __forceinline__ void ktile8(
    const u16* __restrict__ Ab, const u16* __restrict__ Bb,
    u16* curA, u16* curB, u16* nxtA,
    int arow, int brow, int t,
    f32x4 (&acc)[8][4], int wr, int wc, int l15, int l4, int wave, int lane) {
  const int swz = (l15 & 7) << 3;
  const int kc0 = (l4 * 8) ^ swz;
  const int kc1 = (32 + l4 * 8) ^ swz;
  const int kA = (t + 1) * 64;
  const int kB = (t + 2) * 64;
  bf16x8 a[4][2], b[4][2];

  // ---- P0: read a[0..3] (m rows wr*128+0..63), b[0..1]; stage A0(t+1) ----
  ldA4(curA, a, 0, wr, l15, kc0, kc1);
#pragma unroll
  for (int n = 0; n < 2; ++n) {
    const u16* p = curB + (wc * 64 + n * 16 + l15) * 64;
    b[n][0] = *(const bf16x8*)(p + kc0);
    b[n][1] = *(const bf16x8*)(p + kc1);
  }
  if (STAGE_A) stage_half(Ab, nxtA, arow, kA, wave, lane);
  bar();
  MFMA_Q(0, 0)
  bar();

  // ---- P1: read b[2..3]; stage A1(t+1) ----
#pragma unroll
  for (int n = 2; n < 4; ++n) {
    const u16* p = curB + (wc * 64 + n * 16 + l15) * 64;
    b[n][0] = *(const bf16x8*)(p + kc0);
    b[n][1] = *(const bf16x8*)(p + kc1);
  }
  if (STAGE_A) stage_half(Ab, nxtA + HALF, arow + 128, kA, wave, lane);
  bar();
  MFMA_Q(0, 2)
  bar();

  // ---- P2: read a[4..7] (rows wr*128+64..127); stage B0(t+2) into curB ----
  ldA4(curA, a, 64, wr, l15, kc0, kc1);
  if (STAGE_B) stage_half(Bb, curB, brow, kB, wave, lane);
  bar();
  MFMA_Q(4, 0)
  bar();

  // ---- P3: stage B1(t+2); boundary wait ----
  if (STAGE_B) stage_half(Bb, curB + HALF, brow + 128, kB, wave, lane);
  bar();
  MFMA_Q(4, 2)
  if (BOUND >= 0) {
    vmw<BOUND>();
    bar();
  }
}

__global__ __launch_bounds__(512, 2)
void gemm_lse_8ph(const u16* __restrict__ Ab, const u16* __restrict__ Bb,
                  float* __restrict__ S) {
  __shared__ u16 smem[65536];            // 128 KiB
  u16* sA0 = smem;                       // buf0 A (256x64)
  u16* sB0 = smem + 16384;               // buf0 B
  u16* sA1 = smem + 32768;               // buf1 A
  u16* sB1 = smem + 49152;               // buf1 B

  const int tid  = threadIdx.x;
  const int lane = tid & 63;
  const int wave = tid >> 6;                 // 0..7
  const int wr = wave >> 2, wc = wave & 3;   // 2x4 wave grid, 128x64 out each
  const int l15 = lane & 15, l4 = lane >> 4;

  // 2D supertile XCD mapping (round 3, verified: FETCH 2.1GB -> 435MB)
  const int lid  = blockIdx.x;
  const int band = lid & 7;
  const int idx2 = lid >> 3;
  const int bn   = idx2 >> 2;
  const int bm   = band * 4 + (idx2 & 3);
  const int arow = bm * 256, brow = bn * 256;

  f32x4 acc[8][4];
#pragma unroll
  for (int m = 0; m < 8; ++m)
#pragma unroll
    for (int n = 0; n < 4; ++n) acc[m][n] = (f32x4)(0.f);

  // Prologue: A(0), B(0), B(1) = 6 halves (12 loads/thread); vmcnt(4) leaves
  // B(1) in flight, guarantees tile 0 fully landed.
  stage_half(Ab, sA0,        arow,       0, wave, lane);
  stage_half(Ab, sA0 + HALF, arow + 128, 0, wave, lane);
  stage_half(Bb, sB0,        brow,       0, wave, lane);
  stage_half(Bb, sB0 + HALF, brow + 128, 0, wave, lane);
  stage_half(Bb, sB1,        brow,      64, wave, lane);
  stage_half(Bb, sB1 + HALF, brow + 128, 64, wave, lane);
  vmw<4>();
  bar();

#pragma unroll 1
  for (int t0 = 0; t0 < 14; t0 += 2) {
    ktile8<true, true, 4>(Ab, Bb, sA0, sB0, sA1, arow, brow, t0,     acc, wr, wc, l15, l4, wave, lane);
    ktile8<true, true, 4>(Ab, Bb, sA1, sB1, sA0, arow, brow, t0 + 1, acc, wr, wc, l15, l4, wave, lane);
  }
  // t=14: stage A(15) only; boundary drains everything (B(15) staged at t=13).
  ktile8<true, false, 0>(Ab, Bb, sA0, sB0, sA1, arow, brow, 14, acc, wr, wc, l15, l4, wave, lane);
  // t=15: pure compute, no boundary.
  ktile8<false, false, -1>(Ab, Bb, sA1, sB1, sA0, arow, brow, 15, acc, wr, wc, l15, l4, wave, lane);

  // Epilogue: C/D layout col=lane&15, row=(lane>>4)*4+reg (m89-verified).
#pragma unroll
  for (int am = 0; am < 8; ++am) {
#pragma unroll
    for (int j = 0; j < 4; ++j) {
      float v = 0.f;
#pragma unroll
      for (int n = 0; n < 4; ++n) v += __expf(acc[am][n][j]);
      v += __shfl_xor(v, 1);
      v += __shfl_xor(v, 2);
      v += __shfl_xor(v, 4);
      v += __shfl_xor(v, 8);
      if (l15 == 0) {
        const int row = arow + wr * 128 + am * 16 + l4 * 4 + j;
        atomicAdd(&S[row], v);
      }
    }
  }
}

// ---------------- 128^2 fallback (fp32 reg-staged), unchanged ----------------
__global__ __launch_bounds__(256)
void gemm_lse_fb(const float* __restrict__ Af, const float* __restrict__ Bf,
                 float* __restrict__ S) {
  __shared__ u16 As[128 * 64];
  __shared__ u16 Bs[128 * 64];

  const int tid  = threadIdx.x;
  const int lane = tid & 63;
  const int wave = tid >> 6;
  const int wr = wave >> 1, wc = wave & 1;
  const int l15 = lane & 15, l4 = lane >> 4;

  const int lid = blockIdx.x;
  const int wid = (lid & 7) * CHUNK + (lid >> 3);
  const int bm = wid & (NBM - 1);
  const int bn = wid / NBM;

  f32x4 acc[4][4];
#pragma unroll
  for (int m = 0; m < 4; ++m)
#pragma unroll
    for (int n = 0; n < 4; ++n) acc[m][n] = (f32x4)(0.f);

  for (int kt = 0; kt < DMODEL / 64; ++kt) {
    const int k0 = kt * 64;
    {
      const int row = tid >> 4;
      const int kq  = (tid & 15) * 4;
#pragma unroll
      for (int r = 0; r < 8; ++r) {
        const int rr = r * 16 + row;
        const int kd = kq ^ ((rr & 7) << 3);
        float4 a4 = *(const float4*)(Af + (size_t)(bm * 128 + rr) * DMODEL + k0 + kq);
        float4 b4 = *(const float4*)(Bf + (size_t)(bn * 128 + rr) * DMODEL + k0 + kq);
        u16x4 ap = { f2bf(a4.x), f2bf(a4.y), f2bf(a4.z), f2bf(a4.w) };
        u16x4 bp = { f2bf(b4.x), f2bf(b4.y), f2bf(b4.z), f2bf(b4.w) };
        *(u16x4*)&As[rr * 64 + kd] = ap;
        *(u16x4*)&Bs[rr * 64 + kd] = bp;
      }
    }
    __syncthreads();
#pragma unroll
    for (int kk = 0; kk < 2; ++kk) {
      bf16x8 av[4], bv[4];
      const int swz = (l15 & 7) << 3;
      const int kc  = (kk * 32 + l4 * 8) ^ swz;
#pragma unroll
      for (int m = 0; m < 4; ++m)
        av[m] = *(const bf16x8*)&As[(wr * 64 + m * 16 + l15) * 64 + kc];
#pragma unroll
      for (int n = 0; n < 4; ++n)
        bv[n] = *(const bf16x8*)&Bs[(wc * 64 + n * 16 + l15) * 64 + kc];
#pragma unroll
      for (int m = 0; m < 4; ++m)
#pragma unroll
        for (int n = 0; n < 4; ++n)
          acc[m][n] = __builtin_amdgcn_mfma_f32_16x16x32_bf16(av[m], bv[n], acc[m][n], 0, 0, 0);
    }
    __syncthreads();
  }

#pragma unroll
  for (int m = 0; m < 4; ++m) {
#pragma unroll
    for (int j = 0; j < 4; ++j) {
      float v = 0.f;
#pragma unroll
      for (int n = 0; n < 4; ++n) v += __expf(acc[m][n][j]);
      v += __shfl_xor(v, 1);
      v += __shfl_xor(v, 2);
      v += __shfl_xor(v, 4);
      v += __shfl_xor(v, 8);
      if (l15 == 0) {
        const int row = bm * 128 + wr * 64 + m * 16 + l4 * 4 + j;
        atomicAdd(&S[row], v);
      }
    }
  }
}

// ---------------- exact fp32 target score ----------------
__global__ void target_score_k(const float* __restrict__ inp, const float* __restrict__ W,
                               const int* __restrict__ tgt, float* __restrict__ ts) {
  const int gtid = blockIdx.x * blockDim.x + threadIdx.x;
  const int t = gtid >> 6;
  const int lane = threadIdx.x & 63;
  if (t >= TOKENS) return;
  bool allhi0 = true, anylo = false;
  for (int i = 0; i < 64; ++i) {
    if (tgt[2 * i + 1] != 0) allhi0 = false;
    if (tgt[2 * i] != 0) anylo = true;
  }
  const int v = (allhi0 && anylo) ? tgt[2 * t] : tgt[t];
  const float4* xr = (const float4*)(inp + (size_t)t * DMODEL);
  const float4* wr = (const float4*)(W + (size_t)v * DMODEL);
  float s = 0.f;
#pragma unroll
  for (int i = 0; i < 4; ++i) {
    float4 a = xr[lane + 64 * i];
    float4 b = wr[lane + 64 * i];
    s += a.x * b.x + a.y * b.y + a.z * b.z + a.w * b.w;
  }
#pragma unroll
  for (int off = 32; off >= 1; off >>= 1) s += __shfl_xor(s, off);
  if (lane == 0) ts[t] = s;
}

__global__ void finalize_k(const float* __restrict__ S, const float* __restrict__ ts,
                           float* __restrict__ out) {
  __shared__ float red[16];
  float s = 0.f;
  for (int t = threadIdx.x; t < TOKENS; t += blockDim.x) s += __logf(S[t]) - ts[t];
#pragma unroll
  for (int off = 32; off >= 1; off >>= 1) s += __shfl_xor(s, off);
  const int wave = threadIdx.x >> 6, lane = threadIdx.x & 63;
  if (lane == 0) red[wave] = s;
  __syncthreads();
  if (threadIdx.x == 0) {
    float tot = 0.f;
    for (int w = 0; w < (int)(blockDim.x >> 6); ++w) tot += red[w];
    out[0] = tot;
  }
}

extern "C" void kernel_launch(void* const* d_in, const int* in_sizes, int n_in,
                              void* d_out, int out_size, void* d_ws, size_t ws_size,
                              hipStream_t stream) {
  const float* inp = (const float*)d_in[0];
  const float* W   = (const float*)d_in[1];
  const int*   tgt = (const int*)d_in[2];
  float* out = (float*)d_out;

  char* ws = (char*)d_ws;
  float* S  = (float*)ws;
  float* ts = (float*)(ws + 32 * 1024);
  const size_t offA = 64 * 1024;
  const size_t offB = offA + (size_t)TOKENS * DMODEL * 2;
  const size_t need = offB + (size_t)VOCAB * DMODEL * 2;  // ~82.4 MB
  const bool preconv = ws_size >= need;

  hipMemsetAsync(S, 0, TOKENS * sizeof(float), stream);

  if (preconv) {
    u16* Ab = (u16*)(ws + offA);
    u16* Bb = (u16*)(ws + offB);
    convert_to_bf16<<<4096, 256, 0, stream>>>(inp, Ab, (long long)TOKENS * DMODEL);
    convert_to_bf16<<<4096, 256, 0, stream>>>(W, Bb, (long long)VOCAB * DMODEL);
    gemm_lse_8ph<<<NWG2, 512, 0, stream>>>(Ab, Bb, S);
  } else {
    gemm_lse_fb<<<NWG, 256, 0, stream>>>(inp, W, S);
  }
  target_score_k<<<(TOKENS * 64) / 256, 256, 0, stream>>>(inp, W, tgt, ts);
  finalize_k<<<1, 1024, 0, stream>>>(S, ts, out);
}

// Round 5
// 429.254 us; speedup vs baseline: 1.3137x; 1.3137x over previous
//
#include <hip/hip_runtime.h>
#include <stdint.h>

// Fused linear -> logsumexp -> NLL(sum), TOKENS x DMODEL @ (VOCAB x DMODEL)^T.
// Round 5: MX-fp8 GEMM (mfma_scale_f32_16x16x128_f8f6f4, unit scales 0x7F).
//  - A -> e4m3 (scale 1), W -> e4m3 pre-scaled x16 (unscaled by 0.0625 in epilogue).
//  - 128x128 tile, BK=128 (one MFMA-K per step), 4 waves 2x2, 64 KiB dbuf LDS
//    => 2 independent blocks/CU (cross-block overlap; barriers can't give this).
//  - Round-3's proven stage-early 2-barrier loop (8-phase was measured neutral).
//  - Supertile XCD map: band owns 8 bm rows (1 MB A in L2), bn-major sweep.
//  - Swizzle: byte_col ^= (row&7)<<4 both sides (source-preswizzle + read).

#define TOKENS 8192
#define DMODEL 1024
#define VOCAB  32000

// fp8 main geometry
#define NBM8   (TOKENS / 128)   // 64
#define NBN8   (VOCAB / 128)    // 250
#define NWG8   (NBM8 * NBN8)    // 16000 = 8 bands x 2000

// fp32 fallback geometry
#define NBM    (TOKENS / 128)
#define NBN    (VOCAB / 128)
#define NWG    (NBM * NBN)
#define CHUNK  (NWG / 8)

typedef float  f32x4  __attribute__((ext_vector_type(4)));
typedef int    i32x8  __attribute__((ext_vector_type(8)));
typedef __bf16 bf16x8 __attribute__((ext_vector_type(8)));
typedef unsigned short u16;
typedef u16 u16x4 __attribute__((ext_vector_type(4)));

__device__ __forceinline__ u16 f2bf(float f) {
  union { float f; uint32_t u; } v; v.f = f;
  return (u16)((v.u + 0x7FFFu + ((v.u >> 16) & 1u)) >> 16);
}

// fp32 -> OCP e4m3fn, RNE, saturating. Subnormal path via rint(x*512).
__device__ __forceinline__ uint8_t f2e4m3(float x) {
  union { float f; uint32_t u; } v; v.f = x;
  const uint32_t s = (v.u >> 24) & 0x80u;
  const float ax = fabsf(x);
  if (ax >= 464.f) return (uint8_t)(s | 0x7E);       // clamp to 448
  if (ax < 0.015625f) {                               // subnormal region, q*2^-9
    const int q = (int)rintf(ax * 512.f);             // 0..8 (8 -> first normal)
    return (uint8_t)(s | (uint32_t)q);
  }
  uint32_t u = v.u;
  u += 0x000FFFFFu + ((u >> 20) & 1u);                // RNE at mantissa bit 20
  const int E = (int)((u >> 23) & 0xFF) - 127;        // in [-6, 8]
  const uint32_t m3 = (u >> 20) & 0x7u;
  return (uint8_t)(s | (uint32_t)(((E + 7) << 3) | m3));
}

__device__ __forceinline__ void g2lds16(const void* gsrc, void* ldst) {
  __builtin_amdgcn_global_load_lds(
      (const __attribute__((address_space(1))) uint32_t*)(uintptr_t)gsrc,
      (__attribute__((address_space(3))) uint32_t*)(uintptr_t)ldst,
      16, 0, 0);
}

// fp32 -> fp8 conversion pass (8 elems/thread/iter), with scale.
__global__ void convert_to_fp8(const float* __restrict__ in, uint8_t* __restrict__ out,
                               long long n, float scale) {
  long long i0 = ((long long)blockIdx.x * blockDim.x + threadIdx.x) * 8;
  long long stride = (long long)gridDim.x * blockDim.x * 8;
  for (long long base = i0; base < n; base += stride) {
    float4 a = *(const float4*)(in + base);
    float4 b = *(const float4*)(in + base + 4);
    uint8_t r[8] = { f2e4m3(a.x * scale), f2e4m3(a.y * scale),
                     f2e4m3(a.z * scale), f2e4m3(a.w * scale),
                     f2e4m3(b.x * scale), f2e4m3(b.y * scale),
                     f2e4m3(b.z * scale), f2e4m3(b.w * scale) };
    *(uint64_t*)(out + base) = *(const uint64_t*)r;
  }
}

// ---------------- MX-fp8 fused GEMM + exp-row-sum ----------------
// Stage one 128x128-byte fp8 tile: 16 chunks of 8 rows (1 KiB each);
// per thread 4 issues. Source col pre-swizzled, LDS linear (rule #21).
__device__ __forceinline__ void stage_fp8(const uint8_t* __restrict__ G, uint8_t* L,
                                          int grow0, int k0, int wave, int lane) {
#pragma unroll
  for (int i = 0; i < 4; ++i) {
    const int c   = i * 4 + wave;
    const int row = c * 8 + (lane >> 3);
    const int col = ((lane & 7) * 16) ^ ((row & 7) << 4);
    g2lds16(G + (size_t)(grow0 + row) * DMODEL + k0 + col, (void*)(L + c * 1024));
  }
}

// One K-step (K=128): 8+8 ds_read_b128 -> 16 MFMA (16x16x128).
// A-frag layout (by analogy with verified 16x16x32 bf16): row = lane&15,
// k-bytes = (lane>>4)*32 + 0..31. Unit scales 0x7F7F7F7F => x1.0, layout-proof.
__device__ __forceinline__ void kstep_fp8(const uint8_t* As, const uint8_t* Bs,
                                          f32x4 acc[4][4],
                                          int wr, int wc, int l15, int l4) {
  const int swz = (l15 & 7) << 4;
  const int c0 = (l4 * 32) ^ swz;
  const int c1 = (l4 * 32 + 16) ^ swz;
  i32x8 a[4], b[4];
#pragma unroll
  for (int m = 0; m < 4; ++m) {
    const uint8_t* p = As + (wr * 64 + m * 16 + l15) * 128;
    *(uint4*)&a[m]       = *(const uint4*)(p + c0);
    *((uint4*)&a[m] + 1) = *(const uint4*)(p + c1);
  }
#pragma unroll
  for (int n = 0; n < 4; ++n) {
    const uint8_t* p = Bs + (wc * 64 + n * 16 + l15) * 128;
    *(uint4*)&b[n]       = *(const uint4*)(p + c0);
    *((uint4*)&b[n] + 1) = *(const uint4*)(p + c1);
  }
  __builtin_amdgcn_s_setprio(1);
#pragma unroll
  for (int m = 0; m < 4; ++m)
#pragma unroll
    for (int n = 0; n < 4; ++n)
      acc[m][n] = __builtin_amdgcn_mfma_scale_f32_16x16x128_f8f6f4(
          a[m], b[n], acc[m][n], 0, 0,
          0, 0x7F7F7F7F, 0, 0x7F7F7F7F);
  __builtin_amdgcn_s_setprio(0);
}

__global__ __launch_bounds__(256, 2)
void gemm_lse_fp8(const uint8_t* __restrict__ A8, const uint8_t* __restrict__ B8,
                  float* __restrict__ S) {
  __shared__ uint8_t smem[65536];        // 64 KiB: 2 x (A 16K + B 16K)
  uint8_t* A0 = smem;
  uint8_t* B0 = smem + 16384;
  uint8_t* A1 = smem + 32768;
  uint8_t* B1 = smem + 49152;

  const int tid  = threadIdx.x;
  const int lane = tid & 63;
  const int wave = tid >> 6;                 // 0..3
  const int wr = wave >> 1, wc = wave & 1;   // 2x2 wave grid, 64x64 out each
  const int l15 = lane & 15, l4 = lane >> 4;

  // Supertile XCD map: band owns bm in [band*8, band*8+8), bn-major sweep.
  const int lid  = blockIdx.x;
  const int band = lid & 7;
  const int idx2 = lid >> 3;                 // 0..1999
  const int bn   = idx2 >> 3;                // 0..249
  const int bm   = band * 8 + (idx2 & 7);    // 0..63
  const int arow = bm * 128, brow = bn * 128;

  f32x4 acc[4][4];
#pragma unroll
  for (int m = 0; m < 4; ++m)
#pragma unroll
    for (int n = 0; n < 4; ++n) acc[m][n] = (f32x4)(0.f);

  // prologue: stage K-step 0 into buf0
  stage_fp8(A8, A0, arow, 0, wave, lane);
  stage_fp8(B8, B0, brow, 0, wave, lane);

  // 8 K-steps of 128, unrolled x2 for compile-time buffer pointers.
  // Stage-early: loads for t+1 issue before compute(t); the next barrier's
  // vmcnt drain waits on loads issued a full compute phase ago.
#pragma unroll 1
  for (int tt = 0; tt < 4; ++tt) {
    const int t0 = 2 * tt;
    __syncthreads();
    if (t0 + 1 < 8) {
      stage_fp8(A8, A1, arow, (t0 + 1) * 128, wave, lane);
      stage_fp8(B8, B1, brow, (t0 + 1) * 128, wave, lane);
    }
    kstep_fp8(A0, B0, acc, wr, wc, l15, l4);
    __syncthreads();
    if (t0 + 2 < 8) {
      stage_fp8(A8, A0, arow, (t0 + 2) * 128, wave, lane);
      stage_fp8(B8, B0, brow, (t0 + 2) * 128, wave, lane);
    }
    kstep_fp8(A1, B1, acc, wr, wc, l15, l4);
  }

  // Epilogue: C/D layout col=lane&15, row=(lane>>4)*4+reg (m89-verified,
  // shape-determined for f8f6f4 too). Unscale by 1/16 (W was x16).
#pragma unroll
  for (int m = 0; m < 4; ++m) {
#pragma unroll
    for (int j = 0; j < 4; ++j) {
      float v = 0.f;
#pragma unroll
      for (int n = 0; n < 4; ++n) v += __expf(acc[m][n][j] * 0.0625f);
      v += __shfl_xor(v, 1);
      v += __shfl_xor(v, 2);
      v += __shfl_xor(v, 4);
      v += __shfl_xor(v, 8);
      if (l15 == 0) {
        const int row = arow + wr * 64 + m * 16 + l4 * 4 + j;
        atomicAdd(&S[row], v);
      }
    }
  }
}

// ---------------- 128^2 fp32 fallback (ws too small), unchanged ----------------
__global__ __launch_bounds__(256)
void gemm_lse_fb(const float* __restrict__ Af, const float* __restrict__ Bf,
                 float* __restrict__ S) {
  __shared__ u16 As[128 * 64];
  __shared__ u16 Bs[128 * 64];

  const int tid  = threadIdx.x;
  const int lane = tid & 63;
  const int wave = tid >> 6;
  const int wr = wave >> 1, wc = wave & 1;
  const int l15 = lane & 15, l4 = lane >> 4;

  const int lid = blockIdx.x;
  const int wid = (lid & 7) * CHUNK + (lid >> 3);
  const int bm = wid & (NBM - 1);
  const int bn = wid / NBM;

  f32x4 acc[4][4];
#pragma unroll
  for (int m = 0; m < 4; ++m)
#pragma unroll
    for (int n = 0; n < 4; ++n) acc[m][n] = (f32x4)(0.f);

  for (int kt = 0; kt < DMODEL / 64; ++kt) {
    const int k0 = kt * 64;
    {
      const int row = tid >> 4;
      const int kq  = (tid & 15) * 4;
#pragma unroll
      for (int r = 0; r < 8; ++r) {
        const int rr = r * 16 + row;
        const int kd = kq ^ ((rr & 7) << 3);
        float4 a4 = *(const float4*)(Af + (size_t)(bm * 128 + rr) * DMODEL + k0 + kq);
        float4 b4 = *(const float4*)(Bf + (size_t)(bn * 128 + rr) * DMODEL + k0 + kq);
        u16x4 ap = { f2bf(a4.x), f2bf(a4.y), f2bf(a4.z), f2bf(a4.w) };
        u16x4 bp = { f2bf(b4.x), f2bf(b4.y), f2bf(b4.z), f2bf(b4.w) };
        *(u16x4*)&As[rr * 64 + kd] = ap;
        *(u16x4*)&Bs[rr * 64 + kd] = bp;
      }
    }
    __syncthreads();
#pragma unroll
    for (int kk = 0; kk < 2; ++kk) {
      bf16x8 av[4], bv[4];
      const int swz = (l15 & 7) << 3;
      const int kc  = (kk * 32 + l4 * 8) ^ swz;
#pragma unroll
      for (int m = 0; m < 4; ++m)
        av[m] = *(const bf16x8*)&As[(wr * 64 + m * 16 + l15) * 64 + kc];
#pragma unroll
      for (int n = 0; n < 4; ++n)
        bv[n] = *(const bf16x8*)&Bs[(wc * 64 + n * 16 + l15) * 64 + kc];
#pragma unroll
      for (int m = 0; m < 4; ++m)
#pragma unroll
        for (int n = 0; n < 4; ++n)
          acc[m][n] = __builtin_amdgcn_mfma_f32_16x16x32_bf16(av[m], bv[n], acc[m][n], 0, 0, 0);
    }
    __syncthreads();
  }

#pragma unroll
  for (int m = 0; m < 4; ++m) {
#pragma unroll
    for (int j = 0; j < 4; ++j) {
      float v = 0.f;
#pragma unroll
      for (int n = 0; n < 4; ++n) v += __expf(acc[m][n][j]);
      v += __shfl_xor(v, 1);
      v += __shfl_xor(v, 2);
      v += __shfl_xor(v, 4);
      v += __shfl_xor(v, 8);
      if (l15 == 0) {
        const int row = bm * 128 + wr * 64 + m * 16 + l4 * 4 + j;
        atomicAdd(&S[row], v);
      }
    }
  }
}

// ---------------- exact fp32 target score ----------------
__global__ void target_score_k(const float* __restrict__ inp, const float* __restrict__ W,
                               const int* __restrict__ tgt, float* __restrict__ ts) {
  const int gtid = blockIdx.x * blockDim.x + threadIdx.x;
  const int t = gtid >> 6;
  const int lane = threadIdx.x & 63;
  if (t >= TOKENS) return;
  bool allhi0 = true, anylo = false;
  for (int i = 0; i < 64; ++i) {
    if (tgt[2 * i + 1] != 0) allhi0 = false;
    if (tgt[2 * i] != 0) anylo = true;
  }
  const int v = (allhi0 && anylo) ? tgt[2 * t] : tgt[t];
  const float4* xr = (const float4*)(inp + (size_t)t * DMODEL);
  const float4* wr = (const float4*)(W + (size_t)v * DMODEL);
  float s = 0.f;
#pragma unroll
  for (int i = 0; i < 4; ++i) {
    float4 a = xr[lane + 64 * i];
    float4 b = wr[lane + 64 * i];
    s += a.x * b.x + a.y * b.y + a.z * b.z + a.w * b.w;
  }
#pragma unroll
  for (int off = 32; off >= 1; off >>= 1) s += __shfl_xor(s, off);
  if (lane == 0) ts[t] = s;
}

__global__ void finalize_k(const float* __restrict__ S, const float* __restrict__ ts,
                           float* __restrict__ out) {
  __shared__ float red[16];
  float s = 0.f;
  for (int t = threadIdx.x; t < TOKENS; t += blockDim.x) s += __logf(S[t]) - ts[t];
#pragma unroll
  for (int off = 32; off >= 1; off >>= 1) s += __shfl_xor(s, off);
  const int wave = threadIdx.x >> 6, lane = threadIdx.x & 63;
  if (lane == 0) red[wave] = s;
  __syncthreads();
  if (threadIdx.x == 0) {
    float tot = 0.f;
    for (int w = 0; w < (int)(blockDim.x >> 6); ++w) tot += red[w];
    out[0] = tot;
  }
}

extern "C" void kernel_launch(void* const* d_in, const int* in_sizes, int n_in,
                              void* d_out, int out_size, void* d_ws, size_t ws_size,
                              hipStream_t stream) {
  const float* inp = (const float*)d_in[0];
  const float* W   = (const float*)d_in[1];
  const int*   tgt = (const int*)d_in[2];
  float* out = (float*)d_out;

  char* ws = (char*)d_ws;
  float* S  = (float*)ws;
  float* ts = (float*)(ws + 32 * 1024);
  const size_t offA = 64 * 1024;
  const size_t offB = offA + (size_t)TOKENS * DMODEL;          // fp8: 1 B/el
  const size_t need = offB + (size_t)VOCAB * DMODEL;           // ~41.2 MB
  const bool preconv = ws_size >= need;

  hipMemsetAsync(S, 0, TOKENS * sizeof(float), stream);

  if (preconv) {
    uint8_t* A8 = (uint8_t*)(ws + offA);
    uint8_t* B8 = (uint8_t*)(ws + offB);
    convert_to_fp8<<<4096, 256, 0, stream>>>(inp, A8, (long long)TOKENS * DMODEL, 1.0f);
    convert_to_fp8<<<4096, 256, 0, stream>>>(W, B8, (long long)VOCAB * DMODEL, 16.0f);
    gemm_lse_fp8<<<NWG8, 256, 0, stream>>>(A8, B8, S);
  } else {
    gemm_lse_fb<<<NWG, 256, 0, stream>>>(inp, W, S);
  }
  target_score_k<<<(TOKENS * 64) / 256, 256, 0, stream>>>(inp, W, tgt, ts);
  finalize_k<<<1, 1024, 0, stream>>>(S, ts, out);
}

// Round 6
// 376.166 us; speedup vs baseline: 1.4990x; 1.1411x over previous
//
#include <hip/hip_runtime.h>
#include <stdint.h>

// Fused linear -> logsumexp -> NLL(sum), TOKENS x DMODEL @ (VOCAB x DMODEL)^T.
// Round 6: MX-fp8 with 32x32x64 MFMA and frag-major pre-tiled workspace.
//  - Convert kernels write A8/B8 already tiled per (block-row, kstep) in
//    frag-major order: byte = frag*2048 + lane*32 + b, lane = (row&31)+32*(k>>5).
//    => GEMM staging is an identity linear copy (coalesced global_load_lds),
//    and LDS fragment reads (lane*32, +16) are 2-way max = conflict-free.
//  - Block 128x256, BK=64, 4 waves (2x2), wave tile 64x128 = 2x4 of 32x32.
//    48 KiB dbuf LDS => 2 blocks/CU; acc 128 VGPR.
//  - DS floor ~157us, MFMA floor 115us (4686 TF 32x32 MX ceiling).
//  - Supertile XCD map (band owns 8 bm, bn-major sweep) kept from round 5.

#define TOKENS 8192
#define DMODEL 1024
#define VOCAB  32000

// fp8 main geometry
#define NBM32  (TOKENS / 128)   // 64
#define NBN32  (VOCAB / 256)    // 125
#define NWG32  (NBM32 * NBN32)  // 8000 = 8 bands x 1000

// fp32 fallback geometry
#define NBM    (TOKENS / 128)
#define NBN    (VOCAB / 128)
#define NWG    (NBM * NBN)
#define CHUNK  (NWG / 8)

typedef float  f32x4   __attribute__((ext_vector_type(4)));
typedef float  f32x16  __attribute__((ext_vector_type(16)));
typedef int    i32x8   __attribute__((ext_vector_type(8)));
typedef __bf16 bf16x8  __attribute__((ext_vector_type(8)));
typedef unsigned short u16;
typedef u16 u16x4 __attribute__((ext_vector_type(4)));

__device__ __forceinline__ u16 f2bf(float f) {
  union { float f; uint32_t u; } v; v.f = f;
  return (u16)((v.u + 0x7FFFu + ((v.u >> 16) & 1u)) >> 16);
}

// fp32 -> OCP e4m3fn, RNE, saturating.
__device__ __forceinline__ uint8_t f2e4m3(float x) {
  union { float f; uint32_t u; } v; v.f = x;
  const uint32_t s = (v.u >> 24) & 0x80u;
  const float ax = fabsf(x);
  if (ax >= 464.f) return (uint8_t)(s | 0x7E);
  if (ax < 0.015625f) {
    const int q = (int)rintf(ax * 512.f);
    return (uint8_t)(s | (uint32_t)q);
  }
  uint32_t u = v.u;
  u += 0x000FFFFFu + ((u >> 20) & 1u);
  const int E = (int)((u >> 23) & 0xFF) - 127;
  const uint32_t m3 = (u >> 20) & 0x7u;
  return (uint8_t)(s | (uint32_t)(((E + 7) << 3) | m3));
}

__device__ __forceinline__ void g2lds16(const void* gsrc, void* ldst) {
  __builtin_amdgcn_global_load_lds(
      (const __attribute__((address_space(1))) uint32_t*)(uintptr_t)gsrc,
      (__attribute__((address_space(3))) uint32_t*)(uintptr_t)ldst,
      16, 0, 0);
}

// fp32 -> fp8, writing the frag-major tiled layout.
// Tile = (row-block rb of NR rows) x (kstep kt of 64 k): TS = NR*64 bytes.
// Within tile: byte = sub*2048 + l*32 + b, where sub = (row%NR)/32,
// l = (row&31) + 32*(k5>>5), b = k5&31  (k5 = k%64).
__global__ void convert_fp8_tiled(const float* __restrict__ in, uint8_t* __restrict__ out,
                                  long long total, int NR, int log2ts, float scale) {
  const long long step = (long long)gridDim.x * blockDim.x * 8;
  for (long long d = ((long long)blockIdx.x * blockDim.x + threadIdx.x) * 8;
       d < total; d += step) {
    const long long tile = d >> log2ts;
    const int x  = (int)(d & ((1 << log2ts) - 1));
    const int sub = x >> 11;
    const int l   = (x >> 5) & 63;
    const int b0  = x & 31;                     // multiple of 8
    const int rb  = (int)(tile >> 4);
    const int kt  = (int)(tile & 15);
    const int row = rb * NR + sub * 32 + (l & 31);
    const int k   = kt * 64 + (l >> 5) * 32 + b0;
    const float* src = in + (size_t)row * DMODEL + k;
    const float4 f0 = *(const float4*)src;
    const float4 f1 = *(const float4*)(src + 4);
    uint8_t r[8] = { f2e4m3(f0.x * scale), f2e4m3(f0.y * scale),
                     f2e4m3(f0.z * scale), f2e4m3(f0.w * scale),
                     f2e4m3(f1.x * scale), f2e4m3(f1.y * scale),
                     f2e4m3(f1.z * scale), f2e4m3(f1.w * scale) };
    *(uint64_t*)(out + d) = *(const uint64_t*)r;
  }
}

// ---------------- MX-fp8 32x32 fused GEMM + exp-row-sum ----------------
// Identity linear staging: tile data already in LDS-final order.
template <int NCHUNK>
__device__ __forceinline__ void stage_lin(const uint8_t* __restrict__ src, uint8_t* dst,
                                          int wave, int lane) {
#pragma unroll
  for (int p = 0; p < NCHUNK / 4; ++p) {
    const int c = p * 4 + wave;
    g2lds16(src + c * 1024 + lane * 16, (void*)(dst + c * 1024));
  }
}

__device__ __forceinline__ void kstep32(const uint8_t* As, const uint8_t* Bs,
                                        f32x16 (&acc)[2][4],
                                        int wr, int wc, int lane) {
  i32x8 a[2], b[4];
  const uint8_t* ap = As + (wr * 2) * 2048 + lane * 32;
#pragma unroll
  for (int mi = 0; mi < 2; ++mi) {
    *(uint4*)&a[mi]       = *(const uint4*)(ap + mi * 2048);
    *((uint4*)&a[mi] + 1) = *(const uint4*)(ap + mi * 2048 + 16);
  }
  const uint8_t* bp = Bs + (wc * 4) * 2048 + lane * 32;
#pragma unroll
  for (int ni = 0; ni < 4; ++ni) {
    *(uint4*)&b[ni]       = *(const uint4*)(bp + ni * 2048);
    *((uint4*)&b[ni] + 1) = *(const uint4*)(bp + ni * 2048 + 16);
  }
  __builtin_amdgcn_s_setprio(1);
#pragma unroll
  for (int mi = 0; mi < 2; ++mi)
#pragma unroll
    for (int ni = 0; ni < 4; ++ni)
      acc[mi][ni] = __builtin_amdgcn_mfma_scale_f32_32x32x64_f8f6f4(
          a[mi], b[ni], acc[mi][ni], 0, 0,
          0, 0x7F7F7F7F, 0, 0x7F7F7F7F);
  __builtin_amdgcn_s_setprio(0);
}

__global__ __launch_bounds__(256, 2)
void gemm_lse_fp8v2(const uint8_t* __restrict__ A8, const uint8_t* __restrict__ B8,
                    float* __restrict__ S) {
  __shared__ uint8_t smem[49152];        // 48 KiB: A0 8K | B0 16K | A1 8K | B1 16K
  uint8_t* A0 = smem;
  uint8_t* B0 = smem + 8192;
  uint8_t* A1 = smem + 24576;
  uint8_t* B1 = smem + 32768;

  const int tid  = threadIdx.x;
  const int lane = tid & 63;
  const int wave = tid >> 6;                 // 0..3
  const int wr = wave >> 1, wc = wave & 1;   // 2x2 wave grid; wave tile 64x128

  // Supertile XCD map: band owns bm in [band*8, band*8+8), bn-major sweep.
  const int lid  = blockIdx.x;
  const int band = lid & 7;
  const int idx2 = lid >> 3;                 // 0..999
  const int bn   = idx2 >> 3;                // 0..124
  const int bm   = band * 8 + (idx2 & 7);    // 0..63
  const int arow = bm * 128;

  const uint8_t* Abase = A8 + (size_t)(bm * 16) * 8192;
  const uint8_t* Bbase = B8 + (size_t)(bn * 16) * 16384;

  f32x16 acc[2][4];
#pragma unroll
  for (int mi = 0; mi < 2; ++mi)
#pragma unroll
    for (int ni = 0; ni < 4; ++ni) acc[mi][ni] = (f32x16)(0.f);

  // prologue: stage kstep 0 into buf0
  stage_lin<8>(Abase, A0, wave, lane);
  stage_lin<16>(Bbase, B0, wave, lane);

  // 16 ksteps of K=64, unrolled x2 for compile-time buffer pointers.
#pragma unroll 1
  for (int tt = 0; tt < 8; ++tt) {
    const int t0 = 2 * tt;
    __syncthreads();
    if (t0 + 1 < 16) {
      stage_lin<8>(Abase + (size_t)(t0 + 1) * 8192, A1, wave, lane);
      stage_lin<16>(Bbase + (size_t)(t0 + 1) * 16384, B1, wave, lane);
    }
    kstep32(A0, B0, acc, wr, wc, lane);
    __syncthreads();
    if (t0 + 2 < 16) {
      stage_lin<8>(Abase + (size_t)(t0 + 2) * 8192, A0, wave, lane);
      stage_lin<16>(Bbase + (size_t)(t0 + 2) * 16384, B0, wave, lane);
    }
    kstep32(A1, B1, acc, wr, wc, lane);
  }

  // Epilogue: 32x32 C/D layout (m101-verified): col = lane&31,
  // row = (reg&3) + 8*(reg>>2) + 4*(lane>>5). Unscale 1/16 (W was x16).
#pragma unroll
  for (int mi = 0; mi < 2; ++mi) {
#pragma unroll
    for (int r = 0; r < 16; ++r) {
      float v = 0.f;
#pragma unroll
      for (int ni = 0; ni < 4; ++ni) v += __expf(acc[mi][ni][r] * 0.0625f);
      v += __shfl_xor(v, 1);
      v += __shfl_xor(v, 2);
      v += __shfl_xor(v, 4);
      v += __shfl_xor(v, 8);
      v += __shfl_xor(v, 16);
      if ((lane & 31) == 0) {
        const int row = arow + (wr * 2 + mi) * 32 + (r & 3) + 8 * (r >> 2) + 4 * (lane >> 5);
        atomicAdd(&S[row], v);
      }
    }
  }
}

// ---------------- 128^2 fp32 fallback (ws too small), unchanged ----------------
__global__ __launch_bounds__(256)
void gemm_lse_fb(const float* __restrict__ Af, const float* __restrict__ Bf,
                 float* __restrict__ S) {
  __shared__ u16 As[128 * 64];
  __shared__ u16 Bs[128 * 64];

  const int tid  = threadIdx.x;
  const int lane = tid & 63;
  const int wave = tid >> 6;
  const int wr = wave >> 1, wc = wave & 1;
  const int l15 = lane & 15, l4 = lane >> 4;

  const int lid = blockIdx.x;
  const int wid = (lid & 7) * CHUNK + (lid >> 3);
  const int bm = wid & (NBM - 1);
  const int bn = wid / NBM;

  f32x4 acc[4][4];
#pragma unroll
  for (int m = 0; m < 4; ++m)
#pragma unroll
    for (int n = 0; n < 4; ++n) acc[m][n] = (f32x4)(0.f);

  for (int kt = 0; kt < DMODEL / 64; ++kt) {
    const int k0 = kt * 64;
    {
      const int row = tid >> 4;
      const int kq  = (tid & 15) * 4;
#pragma unroll
      for (int r = 0; r < 8; ++r) {
        const int rr = r * 16 + row;
        const int kd = kq ^ ((rr & 7) << 3);
        float4 a4 = *(const float4*)(Af + (size_t)(bm * 128 + rr) * DMODEL + k0 + kq);
        float4 b4 = *(const float4*)(Bf + (size_t)(bn * 128 + rr) * DMODEL + k0 + kq);
        u16x4 ap = { f2bf(a4.x), f2bf(a4.y), f2bf(a4.z), f2bf(a4.w) };
        u16x4 bp = { f2bf(b4.x), f2bf(b4.y), f2bf(b4.z), f2bf(b4.w) };
        *(u16x4*)&As[rr * 64 + kd] = ap;
        *(u16x4*)&Bs[rr * 64 + kd] = bp;
      }
    }
    __syncthreads();
#pragma unroll
    for (int kk = 0; kk < 2; ++kk) {
      bf16x8 av[4], bv[4];
      const int swz = (l15 & 7) << 3;
      const int kc  = (kk * 32 + l4 * 8) ^ swz;
#pragma unroll
      for (int m = 0; m < 4; ++m)
        av[m] = *(const bf16x8*)&As[(wr * 64 + m * 16 + l15) * 64 + kc];
#pragma unroll
      for (int n = 0; n < 4; ++n)
        bv[n] = *(const bf16x8*)&Bs[(wc * 64 + n * 16 + l15) * 64 + kc];
#pragma unroll
      for (int m = 0; m < 4; ++m)
#pragma unroll
        for (int n = 0; n < 4; ++n)
          acc[m][n] = __builtin_amdgcn_mfma_f32_16x16x32_bf16(av[m], bv[n], acc[m][n], 0, 0, 0);
    }
    __syncthreads();
  }

#pragma unroll
  for (int m = 0; m < 4; ++m) {
#pragma unroll
    for (int j = 0; j < 4; ++j) {
      float v = 0.f;
#pragma unroll
      for (int n = 0; n < 4; ++n) v += __expf(acc[m][n][j]);
      v += __shfl_xor(v, 1);
      v += __shfl_xor(v, 2);
      v += __shfl_xor(v, 4);
      v += __shfl_xor(v, 8);
      if (l15 == 0) {
        const int row = bm * 128 + wr * 64 + m * 16 + l4 * 4 + j;
        atomicAdd(&S[row], v);
      }
    }
  }
}

// ---------------- exact fp32 target score ----------------
__global__ void target_score_k(const float* __restrict__ inp, const float* __restrict__ W,
                               const int* __restrict__ tgt, float* __restrict__ ts) {
  const int gtid = blockIdx.x * blockDim.x + threadIdx.x;
  const int t = gtid >> 6;
  const int lane = threadIdx.x & 63;
  if (t >= TOKENS) return;
  bool allhi0 = true, anylo = false;
  for (int i = 0; i < 64; ++i) {
    if (tgt[2 * i + 1] != 0) allhi0 = false;
    if (tgt[2 * i] != 0) anylo = true;
  }
  const int v = (allhi0 && anylo) ? tgt[2 * t] : tgt[t];
  const float4* xr = (const float4*)(inp + (size_t)t * DMODEL);
  const float4* wr = (const float4*)(W + (size_t)v * DMODEL);
  float s = 0.f;
#pragma unroll
  for (int i = 0; i < 4; ++i) {
    float4 a = xr[lane + 64 * i];
    float4 b = wr[lane + 64 * i];
    s += a.x * b.x + a.y * b.y + a.z * b.z + a.w * b.w;
  }
#pragma unroll
  for (int off = 32; off >= 1; off >>= 1) s += __shfl_xor(s, off);
  if (lane == 0) ts[t] = s;
}

__global__ void finalize_k(const float* __restrict__ S, const float* __restrict__ ts,
                           float* __restrict__ out) {
  __shared__ float red[16];
  float s = 0.f;
  for (int t = threadIdx.x; t < TOKENS; t += blockDim.x) s += __logf(S[t]) - ts[t];
#pragma unroll
  for (int off = 32; off >= 1; off >>= 1) s += __shfl_xor(s, off);
  const int wave = threadIdx.x >> 6, lane = threadIdx.x & 63;
  if (lane == 0) red[wave] = s;
  __syncthreads();
  if (threadIdx.x == 0) {
    float tot = 0.f;
    for (int w = 0; w < (int)(blockDim.x >> 6); ++w) tot += red[w];
    out[0] = tot;
  }
}

extern "C" void kernel_launch(void* const* d_in, const int* in_sizes, int n_in,
                              void* d_out, int out_size, void* d_ws, size_t ws_size,
                              hipStream_t stream) {
  const float* inp = (const float*)d_in[0];
  const float* W   = (const float*)d_in[1];
  const int*   tgt = (const int*)d_in[2];
  float* out = (float*)d_out;

  char* ws = (char*)d_ws;
  float* S  = (float*)ws;
  float* ts = (float*)(ws + 32 * 1024);
  const size_t offA = 64 * 1024;
  const long long totalA = (long long)TOKENS * DMODEL;   // 8,388,608 bytes fp8
  const long long totalB = (long long)VOCAB * DMODEL;    // 32,768,000 bytes fp8
  const size_t offB = offA + (size_t)totalA;
  const size_t need = offB + (size_t)totalB;             // ~41.2 MB
  const bool preconv = ws_size >= need;

  hipMemsetAsync(S, 0, TOKENS * sizeof(float), stream);

  if (preconv) {
    uint8_t* A8 = (uint8_t*)(ws + offA);
    uint8_t* B8 = (uint8_t*)(ws + offB);
    convert_fp8_tiled<<<4096, 256, 0, stream>>>(inp, A8, totalA, 128, 13, 1.0f);
    convert_fp8_tiled<<<16000, 256, 0, stream>>>(W, B8, totalB, 256, 14, 16.0f);
    gemm_lse_fp8v2<<<NWG32, 256, 0, stream>>>(A8, B8, S);
  } else {
    gemm_lse_fb<<<NWG, 256, 0, stream>>>(inp, W, S);
  }
  target_score_k<<<(TOKENS * 64) / 256, 256, 0, stream>>>(inp, W, tgt, ts);
  finalize_k<<<1, 1024, 0, stream>>>(S, ts, out);
}